// Round 1
// baseline (169.046 us; speedup 1.0000x reference)
//
#include <hip/hip_runtime.h>

static constexpr float EPSF = 1e-6f;

// Coefficient layout in workspace:
//   coef[((set*3 + ch)*32 + line)*64 + k],  k in [0,32): p_i = 1/denom_i,
//                                           k in [32,64): s_i = c*_i (== a_i/denom_i)
// Sets 0..5  : x-direction, t = 0.1*set,          dt = DT/2 = 0.05
// Sets 6..10 : y-direction, t = 0.1*(set-6)+0.05, dt = DT   = 0.10

__global__ __launch_bounds__(64) void coef_kernel(
    const float* __restrict__ alpha_base, const float* __restrict__ beta_base,
    const float* __restrict__ alpha_tc,   const float* __restrict__ beta_tc,
    float* __restrict__ coef)
{
    int gid  = blockIdx.x * 64 + threadIdx.x;
    int pair = gid >> 5;          // (set,ch) pair index, 0..32
    int line = gid & 31;
    if (pair >= 33) return;
    int set = pair / 3;
    int ch  = pair % 3;
    bool isX = (set < 6);
    float t  = isX ? 0.1f * (float)set : 0.1f * (float)(set - 6) + 0.05f;
    float dt = isX ? 0.05f : 0.1f;

    const float* base = isX ? alpha_base : alpha_base; // placeholder, fixed below
    const float* tc;
    if (isX) { base = alpha_base; tc = alpha_tc; }
    else     { base = beta_base;  tc = beta_tc;  }

    // gather the coefficient line along the solve axis
    float c[32];
    if (isX) {
        const float* bp = base + (ch * 32 + line) * 32;  // alpha[ch][line][i]
        const float* tp = tc   + (ch * 32 + line) * 32;
        #pragma unroll
        for (int i = 0; i < 32; ++i) {
            float v = fmaf(tp[i], t, bp[i]);
            c[i] = fmaxf(v, EPSF);
        }
    } else {
        const float* bp = base + ch * 1024 + line;       // beta[ch][i][line]
        const float* tp = tc   + ch * 1024 + line;
        #pragma unroll
        for (int i = 0; i < 32; ++i) {
            float v = fmaf(tp[i * 32], t, bp[i * 32]);
            c[i] = fmaxf(v, EPSF);
        }
    }

    // replicate-pad 3-tap mean, scaled by dt (dh = 1)
    float cs[32];
    #pragma unroll
    for (int i = 0; i < 32; ++i) {
        float l = (i == 0)  ? c[0]  : c[i - 1];
        float r = (i == 31) ? c[31] : c[i + 1];
        cs[i] = (l + c[i] + r) / 3.0f * dt;
    }

    // Thomas forward coefficient recurrence.
    // b_i = 1 + 2cs_i, except b_0 = 1 + cs_0, b_31 = 1 + cs_31; a_i = c_i = -cs_i, a_0 := 0
    float p[32], s[32];
    {
        float den = (1.0f + cs[0]) + EPSF;       // a_0 = 0
        p[0] = 1.0f / den;
        s[0] = -cs[0] * p[0];
        #pragma unroll
        for (int i = 1; i < 32; ++i) {
            float bi = (i == 31) ? (1.0f + cs[31]) : fmaf(2.0f, cs[i], 1.0f);
            float ai = -cs[i];
            float d  = (bi - ai * s[i - 1]) + EPSF;
            float pi = 1.0f / d;
            p[i] = pi;
            s[i] = ai * pi;                       // a_i == c_i  ->  s_i == c*_i
        }
    }

    float* out = coef + ((set * 3 + ch) * 32 + line) * 64;
    #pragma unroll
    for (int i = 0; i < 32; ++i) { out[i] = p[i]; out[32 + i] = s[i]; }
}

// ---------------------------------------------------------------------------
// Main kernel: one block = 8 slabs (same channel), one thread = one line.
// LDS tile stride 33 -> both row (stride 1) and column (stride 33) accesses
// are bank-conflict-free (bank = (line + i) % 32).
// ---------------------------------------------------------------------------

template <int STRIDE>
__device__ __forceinline__ void solve_line(float* base, const float* __restrict__ cf)
{
    float p[32], s[32];
    const float4* c4 = reinterpret_cast<const float4*>(cf);
    #pragma unroll
    for (int j = 0; j < 8; ++j) {
        float4 v = c4[j];
        p[4 * j + 0] = v.x; p[4 * j + 1] = v.y; p[4 * j + 2] = v.z; p[4 * j + 3] = v.w;
    }
    #pragma unroll
    for (int j = 0; j < 8; ++j) {
        float4 v = c4[8 + j];
        s[4 * j + 0] = v.x; s[4 * j + 1] = v.y; s[4 * j + 2] = v.z; s[4 * j + 3] = v.w;
    }

    float d[32];
    #pragma unroll
    for (int i = 0; i < 32; ++i) d[i] = base[i * STRIDE];

    // forward sweep: ds_i = d_i * p_i - s_i * ds_{i-1}
    d[0] = d[0] * p[0];
    #pragma unroll
    for (int i = 1; i < 32; ++i) d[i] = fmaf(d[i], p[i], -s[i] * d[i - 1]);

    // backward sweep: x_i = ds_i - s_i * x_{i+1}   (x_31 = ds_31)
    #pragma unroll
    for (int i = 30; i >= 0; --i) d[i] = fmaf(-s[i], d[i + 1], d[i]);

    #pragma unroll
    for (int i = 0; i < 32; ++i) base[i * STRIDE] = d[i];
}

__global__ __launch_bounds__(256, 3) void diff_kernel(
    const float* __restrict__ u_in, float* __restrict__ u_out,
    const float* __restrict__ coef, int blocksPerCh)
{
    __shared__ float tile[8 * 1056];   // 8 slabs, 32 rows x stride 33
    const int tid = threadIdx.x;
    const int bid = blockIdx.x;
    const int ch  = bid / blocksPerCh;
    const int b0  = (bid % blocksPerCh) * 8;

    // ---- load 8 slabs (coalesced float4) ----
    {
        const int r  = tid >> 3;
        const int c4 = (tid & 7) << 2;
        #pragma unroll
        for (int it = 0; it < 8; ++it) {
            const int slab = (b0 + it) * 3 + ch;
            const float4 v = reinterpret_cast<const float4*>(u_in + slab * 1024)[tid];
            float* dst = &tile[it * 1056 + r * 33 + c4];
            dst[0] = v.x; dst[1] = v.y; dst[2] = v.z; dst[3] = v.w;
        }
    }
    __syncthreads();

    const int ls = tid >> 5;    // local slab
    const int ln = tid & 31;    // line index
    float* tb = &tile[ls * 1056];
    const float* cbase = coef + (ch * 32 + ln) * 64;   // + set*6144

    for (int step = 0; step < 5; ++step) {
        // x half-step (alpha set = step)
        solve_line<1>(tb + ln * 33, cbase + step * 6144);
        __syncthreads();
        // y full-step (beta set = 6 + step)
        solve_line<33>(tb + ln, cbase + (6 + step) * 6144);
        __syncthreads();
        // x half-step (alpha set = step + 1)
        solve_line<1>(tb + ln * 33, cbase + (step + 1) * 6144);
        __syncthreads();
    }

    // ---- store back (coalesced float4) ----
    {
        const int r  = tid >> 3;
        const int c4 = (tid & 7) << 2;
        #pragma unroll
        for (int it = 0; it < 8; ++it) {
            const int slab = (b0 + it) * 3 + ch;
            const float* s_ = &tile[it * 1056 + r * 33 + c4];
            float4 v; v.x = s_[0]; v.y = s_[1]; v.z = s_[2]; v.w = s_[3];
            reinterpret_cast<float4*>(u_out + slab * 1024)[tid] = v;
        }
    }
}

extern "C" void kernel_launch(void* const* d_in, const int* in_sizes, int n_in,
                              void* d_out, int out_size, void* d_ws, size_t ws_size,
                              hipStream_t stream)
{
    const float* u   = (const float*)d_in[0];
    const float* ab  = (const float*)d_in[1];
    const float* bb  = (const float*)d_in[2];
    const float* atc = (const float*)d_in[3];
    const float* btc = (const float*)d_in[4];
    float* out  = (float*)d_out;
    float* coef = (float*)d_ws;    // 11*3*32*64 floats = 270336 B

    const int B = in_sizes[0] / (3 * 32 * 32);   // 2048
    const int blocksPerCh = B / 8;               // 256

    coef_kernel<<<17, 64, 0, stream>>>(ab, bb, atc, btc, coef);
    diff_kernel<<<3 * blocksPerCh, 256, 0, stream>>>(u, out, coef, blocksPerCh);
}

// Round 2
// 115.904 us; speedup vs baseline: 1.4585x; 1.4585x over previous
//
#include <hip/hip_runtime.h>

static constexpr float EPSF = 1e-6f;

// Transposed coefficient tables (lane-coherent loads in the main kernel):
//   pT [(set*3+ch)*1024 + k*32 + ln]  = 1/denom_k        for solve-line ln
//   snT[(set*3+ch)*1024 + k*32 + ln]  = -c*_k (== -a_k/denom_k)
// Sets 0..5  : x-direction, t = 0.1*set,          dt = DT/2 = 0.05
// Sets 6..10 : y-direction, t = 0.1*(set-6)+0.05, dt = DT   = 0.10

__global__ __launch_bounds__(64) void coef_kernel(
    const float* __restrict__ alpha_base, const float* __restrict__ beta_base,
    const float* __restrict__ alpha_tc,   const float* __restrict__ beta_tc,
    float* __restrict__ pT, float* __restrict__ snT)
{
    int gid  = blockIdx.x * 64 + threadIdx.x;
    int pair = gid >> 5;          // (set,ch) pair index, 0..32
    int ln   = gid & 31;
    if (pair >= 33) return;
    int set = pair / 3;
    int ch  = pair % 3;
    bool isX = (set < 6);
    float t  = isX ? 0.1f * (float)set : 0.1f * (float)(set - 6) + 0.05f;
    float dt = isX ? 0.05f : 0.1f;

    const float* bp; const float* tp; int stride;
    if (isX) { bp = alpha_base + (ch * 32 + ln) * 32; tp = alpha_tc + (ch * 32 + ln) * 32; stride = 1; }
    else     { bp = beta_base  + ch * 1024 + ln;      tp = beta_tc  + ch * 1024 + ln;      stride = 32; }

    float c[32];
    #pragma unroll
    for (int i = 0; i < 32; ++i)
        c[i] = fmaxf(fmaf(tp[i * stride], t, bp[i * stride]), EPSF);

    // replicate-pad 3-tap mean, scaled by dt (dh = 1)
    float cs[32];
    #pragma unroll
    for (int i = 0; i < 32; ++i) {
        float l = (i == 0)  ? c[0]  : c[i - 1];
        float r = (i == 31) ? c[31] : c[i + 1];
        cs[i] = (l + c[i] + r) / 3.0f * dt;
    }

    // Thomas coefficient recurrence. b_i = 1+2cs_i (ends 1+cs), a_i = c_i = -cs_i, a_0 := 0
    float p[32], sn[32];
    {
        float den = (1.0f + cs[0]) + EPSF;
        p[0]  = 1.0f / den;
        sn[0] = cs[0] * p[0];                  // -( -cs0 * p0 )
        float sprev = -sn[0];                  // s_{i-1} = c*_{i-1}
        #pragma unroll
        for (int i = 1; i < 32; ++i) {
            float bi = (i == 31) ? (1.0f + cs[31]) : fmaf(2.0f, cs[i], 1.0f);
            float ai = -cs[i];
            float d  = (bi - ai * sprev) + EPSF;
            float pi = 1.0f / d;
            p[i]  = pi;
            float si = ai * pi;                // s_i = c*_i
            sn[i] = -si;
            sprev = si;
        }
    }

    float* po = pT  + (set * 3 + ch) * 1024 + ln;
    float* so = snT + (set * 3 + ch) * 1024 + ln;
    #pragma unroll
    for (int i = 0; i < 32; ++i) { po[i * 32] = p[i]; so[i * 32] = sn[i]; }
}

// ---------------------------------------------------------------------------
// Register-resident Thomas solve along one 32-line held in d[32].
// pb/sb point at pT/snT for this (set,ch,ln): element k at offset k*32
// (lane-coherent: lanes ln=0..31 read consecutive floats; imm offsets k*128B).
// ---------------------------------------------------------------------------
__device__ __forceinline__ void solve_ln(float d[32],
                                         const float* __restrict__ pb,
                                         const float* __restrict__ sb)
{
    float sn[32];
    #pragma unroll
    for (int i = 0; i < 32; ++i) sn[i] = sb[i * 32];

    float prev = d[0] * pb[0];
    d[0] = prev;
    #pragma unroll
    for (int i = 1; i < 32; ++i) {
        prev = fmaf(sn[i], prev, d[i] * pb[i * 32]);   // 4-cyc chain; mul independent
        d[i] = prev;
    }
    #pragma unroll
    for (int i = 30; i >= 0; --i)
        d[i] = fmaf(sn[i], d[i + 1], d[i]);
}

// ---------------------------------------------------------------------------
// Main kernel: 256 threads = 8 slabs (same channel), one thread = one row,
// row lives in registers across all 15 solves. LDS only for the 5 y-transposes
// and coalesced global load/store. Tile stride 33 -> conflict-free both ways.
// ---------------------------------------------------------------------------
__global__ __launch_bounds__(256, 3) void diff_kernel(
    const float* __restrict__ u_in, float* __restrict__ u_out,
    const float* __restrict__ pT, const float* __restrict__ snT,
    int blocksPerCh)
{
    __shared__ float tile[8 * 1056];   // 8 slabs, 32 rows x stride 33
    const int tid = threadIdx.x;
    const int bid = blockIdx.x;
    const int ch  = bid / blocksPerCh;
    const int b0  = (bid % blocksPerCh) * 8;

    // ---- coalesced load into LDS ----
    {
        const int r  = tid >> 3;
        const int c4 = (tid & 7) << 2;
        #pragma unroll
        for (int it = 0; it < 8; ++it) {
            const int slab = (b0 + it) * 3 + ch;
            const float4 v = reinterpret_cast<const float4*>(u_in + slab * 1024)[tid];
            float* dst = &tile[it * 1056 + r * 33 + c4];
            dst[0] = v.x; dst[1] = v.y; dst[2] = v.z; dst[3] = v.w;
        }
    }
    __syncthreads();

    const int ls = tid >> 5;    // local slab
    const int ln = tid & 31;    // row (x-phase) / column (y-phase) index
    float* tb = &tile[ls * 1056];
    const float* pB = pT  + ch * 1024 + ln;   // + set*3072
    const float* sB = snT + ch * 1024 + ln;

    float d[32];
    #pragma unroll
    for (int i = 0; i < 32; ++i) d[i] = tb[ln * 33 + i];

    // x half-step at t=0 (set 0)
    solve_ln(d, pB, sB);

    for (int step = 0; step < 5; ++step) {
        // ---- y full-step (set 6+step) ----
        #pragma unroll
        for (int i = 0; i < 32; ++i) tb[ln * 33 + i] = d[i];
        __syncthreads();
        #pragma unroll
        for (int i = 0; i < 32; ++i) d[i] = tb[i * 33 + ln];
        {
            const int off = (6 + step) * 3072;
            solve_ln(d, pB + off, sB + off);
        }
        #pragma unroll
        for (int i = 0; i < 32; ++i) tb[i * 33 + ln] = d[i];
        __syncthreads();
        #pragma unroll
        for (int i = 0; i < 32; ++i) d[i] = tb[ln * 33 + i];

        // ---- x half-steps: xb_step and xa_{step+1} share set step+1 ----
        {
            const int off = (step + 1) * 3072;
            solve_ln(d, pB + off, sB + off);
            if (step < 4) solve_ln(d, pB + off, sB + off);
        }
    }

    // ---- coalesced store ----
    #pragma unroll
    for (int i = 0; i < 32; ++i) tb[ln * 33 + i] = d[i];
    __syncthreads();
    {
        const int r  = tid >> 3;
        const int c4 = (tid & 7) << 2;
        #pragma unroll
        for (int it = 0; it < 8; ++it) {
            const int slab = (b0 + it) * 3 + ch;
            const float* s_ = &tile[it * 1056 + r * 33 + c4];
            float4 v; v.x = s_[0]; v.y = s_[1]; v.z = s_[2]; v.w = s_[3];
            reinterpret_cast<float4*>(u_out + slab * 1024)[tid] = v;
        }
    }
}

extern "C" void kernel_launch(void* const* d_in, const int* in_sizes, int n_in,
                              void* d_out, int out_size, void* d_ws, size_t ws_size,
                              hipStream_t stream)
{
    const float* u   = (const float*)d_in[0];
    const float* ab  = (const float*)d_in[1];
    const float* bb  = (const float*)d_in[2];
    const float* atc = (const float*)d_in[3];
    const float* btc = (const float*)d_in[4];
    float* out = (float*)d_out;
    float* pT  = (float*)d_ws;                 // 33*1024 floats = 135168 B
    float* snT = pT + 33 * 1024;               // another 135168 B

    const int B = in_sizes[0] / (3 * 32 * 32);   // 2048
    const int blocksPerCh = B / 8;               // 256

    coef_kernel<<<17, 64, 0, stream>>>(ab, bb, atc, btc, pT, snT);
    diff_kernel<<<3 * blocksPerCh, 256, 0, stream>>>(u, out, pT, snT, blocksPerCh);
}